// Round 1
// baseline (339.646 us; speedup 1.0000x reference)
//
#include <hip/hip_runtime.h>
#include <hip/hip_bf16.h>

typedef _Float16 half4_t  __attribute__((ext_vector_type(4)));
typedef _Float16 half8_t  __attribute__((ext_vector_type(8)));
typedef float    float4_t __attribute__((ext_vector_type(4)));

#define MFMA16x32(a, b, c) __builtin_amdgcn_mfma_f32_16x16x32_f16(a, b, c, 0, 0, 0)
#define MFMA16x16(a, b, c) __builtin_amdgcn_mfma_f32_16x16x16f16(a, b, c, 0, 0, 0)

static constexpr int Bn = 4, Tn = 4096, Sn = 4096, En = 64, Hn = 320, Cn = 768;

__device__ __forceinline__ void async16(const _Float16* g, _Float16* l) {
  __builtin_amdgcn_global_load_lds(
      (const __attribute__((address_space(1))) void*)g,
      (__attribute__((address_space(3))) void*)l, 16, 0, 0);
}

// ---------------------------------------------------------------------------
// Projection: OUT[M x N] = A[M x KTOT] * W[N x KTOT]^T, fp32 in -> fp16 out.
// MODE 0: Q (scale 1/8, natural [m][64]); MODE 1: K (natural [m][64]);
// MODE 2: V (swizzled fragment-block layout for flash PV B-operand).
// WG tile: 128 m x NT n; wave w owns m-tiles {2w, 2w+1} x all n-tiles.
// ---------------------------------------------------------------------------
template <int KTOT, int NT, int MODE>
__global__ __launch_bounds__(256, 2)
void proj_kernel(const float* __restrict__ A, const float* __restrict__ W,
                 _Float16* __restrict__ out) {
  constexpr int NTILES = NT / 16;
  constexpr int NCH = KTOT / 64;
  __shared__ alignas(16) _Float16 Ach[128 * 72];  // padded stride 72 halves
  __shared__ alignas(16) _Float16 Bch[NT * 72];

  const int tid = threadIdx.x;
  const int w = tid >> 6, lane = tid & 63;
  const int G = lane >> 4, l15 = lane & 15;
  const int m0 = blockIdx.x * 128;
  const int n0 = blockIdx.y * NT;

  float4_t acc[2][NTILES];
#pragma unroll
  for (int i = 0; i < 2; ++i)
#pragma unroll
    for (int nt = 0; nt < NTILES; ++nt) acc[i][nt] = {0.f, 0.f, 0.f, 0.f};

  for (int kc = 0; kc < NCH; ++kc) {
    __syncthreads();  // protect LDS from previous chunk's readers
    // stage A chunk [128][64] fp32 -> fp16
#pragma unroll
    for (int t = 0; t < 8; ++t) {
      int idx = tid + t * 256;
      int row = idx >> 4, c4 = idx & 15;
      float4_t v = *(const float4_t*)(A + (size_t)(m0 + row) * KTOT + kc * 64 + c4 * 4);
      half4_t h = {(_Float16)v[0], (_Float16)v[1], (_Float16)v[2], (_Float16)v[3]};
      *(half4_t*)(Ach + row * 72 + c4 * 4) = h;
    }
    // stage B chunk [NT][64] fp32 -> fp16
#pragma unroll
    for (int t = 0; t < NTILES; ++t) {
      int idx = tid + t * 256;
      int row = idx >> 4, c4 = idx & 15;
      float4_t v = *(const float4_t*)(W + (size_t)(n0 + row) * KTOT + kc * 64 + c4 * 4);
      half4_t h = {(_Float16)v[0], (_Float16)v[1], (_Float16)v[2], (_Float16)v[3]};
      *(half4_t*)(Bch + row * 72 + c4 * 4) = h;
    }
    __syncthreads();
#pragma unroll
    for (int c = 0; c < 2; ++c) {
      half8_t af[2];
#pragma unroll
      for (int i = 0; i < 2; ++i)
        af[i] = *(const half8_t*)(Ach + ((2 * w + i) * 16 + l15) * 72 + c * 32 + 8 * G);
#pragma unroll
      for (int nt = 0; nt < NTILES; ++nt) {
        half8_t bf = *(const half8_t*)(Bch + (nt * 16 + l15) * 72 + c * 32 + 8 * G);
#pragma unroll
        for (int i = 0; i < 2; ++i) acc[i][nt] = MFMA16x32(af[i], bf, acc[i][nt]);
      }
    }
  }

  if (MODE <= 1) {
    const float sc = (MODE == 0) ? 0.125f : 1.0f;  // fold 1/sqrt(64) into Q
#pragma unroll
    for (int i = 0; i < 2; ++i)
#pragma unroll
      for (int nt = 0; nt < NTILES; ++nt)
#pragma unroll
        for (int r = 0; r < 4; ++r) {
          int m = m0 + (2 * w + i) * 16 + 4 * G + r;
          out[(size_t)m * 64 + nt * 16 + l15] = (_Float16)(acc[i][nt][r] * sc);
        }
  } else {
    // V swizzle: block(cidx, htg, j): 64 lanes x 4 halves; lane slot L holds
    // (h = htg*16 + (L&15), s = cidx*64 + j*16 + 4*(L>>4) + r) -- exactly our C-regs.
#pragma unroll
    for (int i = 0; i < 2; ++i) {
      int sg = m0 + (2 * w + i) * 16;
      int cidx = sg >> 6;
      int jj = (sg >> 4) & 3;
#pragma unroll
      for (int nt = 0; nt < NTILES; ++nt) {
        int htg = blockIdx.y * NTILES + nt;
        half4_t h = {(_Float16)acc[i][nt][0], (_Float16)acc[i][nt][1],
                     (_Float16)acc[i][nt][2], (_Float16)acc[i][nt][3]};
        *(half4_t*)(out + (size_t)cidx * 20480 + htg * 1024 + jj * 256 + lane * 4) = h;
      }
    }
  }
}

// ---------------------------------------------------------------------------
// Flash cross-attention. One WG (4 waves) per (b, 64-query block).
// S^T = K*Q^T (mfma 16x16x32 f16), partitioned by s-tile across waves;
// exp() in regs feeds PV A-frags directly (C-layout == A-layout for K=16);
// PV partitioned by h (80 h per wave) so V frags are never duplicated.
// No max-subtraction (scores bounded ~|2|); normalize by l at the end.
// ---------------------------------------------------------------------------
__global__ __launch_bounds__(256, 1)
void flash_kernel(const _Float16* __restrict__ Qg, const _Float16* __restrict__ Kg,
                  const _Float16* __restrict__ Vt, float* __restrict__ out) {
  __shared__ alignas(16) _Float16 kbuf[2][64 * 72];   // padded: 2-way (free) banks
  __shared__ alignas(16) _Float16 vbuf[2][20480];     // swizzled frag blocks
  __shared__ alignas(16) _Float16 pbuf[2][4096];      // 16 frag blocks x 256 halves
  __shared__ alignas(16) float lred[4][64];

  const int tid = threadIdx.x;
  const int w = tid >> 6, lane = tid & 63;
  const int G = lane >> 4, l15 = lane & 15;
  const int bi = blockIdx.x;
  const int xcd = bi & 7, sl = bi >> 3;
  const int b = xcd >> 1;                         // batch pinned per XCD-pair (L2 locality)
  const int tblk = ((((xcd & 1) << 5) | sl)) * 64;

  // Q B-fragments: held in registers for the whole kernel (4 t-tiles x 2 ksteps)
  half8_t qf[4][2];
#pragma unroll
  for (int i = 0; i < 4; ++i)
#pragma unroll
    for (int c = 0; c < 2; ++c)
      qf[i][c] = *(const half8_t*)(Qg + (size_t)(b * Tn + tblk + i * 16 + l15) * 64 +
                                   c * 32 + 8 * G);

  float4_t oacc[4][5];
#pragma unroll
  for (int i = 0; i < 4; ++i)
#pragma unroll
    for (int ht = 0; ht < 5; ++ht) oacc[i][ht] = {0.f, 0.f, 0.f, 0.f};
  float la[4] = {0.f, 0.f, 0.f, 0.f};

  const size_t vbase = (size_t)b * Sn * Hn;  // halves; chunk stride = 20480 halves

  // prologue: stage chunk 0 into buffer 0
  {
#pragma unroll
    for (int r = 0; r < 10; ++r) {
      int off = (w * 10 + r) * 512 + lane * 8;
      async16(Vt + vbase + off, &vbuf[0][off]);
    }
#pragma unroll
    for (int it = 0; it < 2; ++it) {
      int idx = tid + it * 256;
      int r = idx >> 3, c8 = idx & 7;
      uint4 kv = *(const uint4*)(Kg + (size_t)(b * Sn + r) * 64 + c8 * 8);
      *(uint4*)(&kbuf[0][r * 72 + c8 * 8]) = kv;
    }
  }
  __syncthreads();

  for (int n = 0; n < 64; ++n) {
    const int cbuf = n & 1;
    const bool more = (n + 1 < 64);
    uint4 kst[2];
    if (more) {  // prefetch next K chunk into registers (drained at ds_write)
#pragma unroll
      for (int it = 0; it < 2; ++it) {
        int idx = tid + it * 256;
        int r = idx >> 3, c8 = idx & 7;
        kst[it] = *(const uint4*)(Kg + (size_t)(b * Sn + (n + 1) * 64 + r) * 64 + c8 * 8);
      }
    }

    // ---- S^T phase: wave w computes S^T[s-tile w][all 64 t] ----
    float4_t sa[4];
#pragma unroll
    for (int i = 0; i < 4; ++i) sa[i] = {0.f, 0.f, 0.f, 0.f};
#pragma unroll
    for (int c = 0; c < 2; ++c) {
      half8_t af = *(const half8_t*)(&kbuf[cbuf][(w * 16 + l15) * 72 + c * 32 + 8 * G]);
#pragma unroll
      for (int i = 0; i < 4; ++i) sa[i] = MFMA16x32(af, qf[i][c], sa[i]);
    }
#pragma unroll
    for (int i = 0; i < 4; ++i) {
      float e0 = __expf(sa[i][0]);
      float e1 = __expf(sa[i][1]);
      float e2 = __expf(sa[i][2]);
      float e3 = __expf(sa[i][3]);
      la[i] += (e0 + e1) + (e2 + e3);
      half4_t p = {(_Float16)e0, (_Float16)e1, (_Float16)e2, (_Float16)e3};
      *(half4_t*)(&pbuf[cbuf][(i * 4 + w) * 256 + lane * 4]) = p;  // == PV A-frag
    }
    __syncthreads();  // P visible to all waves

    // issue V DMA for next chunk here so it overlaps the PV phase
    if (more) {
      const size_t voff = vbase + (size_t)(n + 1) * 20480;
#pragma unroll
      for (int r = 0; r < 10; ++r) {
        int off = (w * 10 + r) * 512 + lane * 8;
        async16(Vt + voff + off, &vbuf[1 - cbuf][off]);
      }
    }

    // ---- PV phase: wave w owns h in [w*80, w*80+80) ----
#pragma unroll
    for (int j = 0; j < 4; ++j) {
      half4_t pa[4];
#pragma unroll
      for (int i = 0; i < 4; ++i)
        pa[i] = *(const half4_t*)(&pbuf[cbuf][(i * 4 + j) * 256 + lane * 4]);
#pragma unroll
      for (int ht = 0; ht < 5; ++ht) {
        half4_t vb = *(const half4_t*)(&vbuf[cbuf][(w * 5 + ht) * 1024 + j * 256 + lane * 4]);
#pragma unroll
        for (int i = 0; i < 4; ++i) oacc[i][ht] = MFMA16x16(pa[i], vb, oacc[i][ht]);
      }
    }

    if (more) {  // write next K chunk (kbuf[1-cbuf] readers finished long ago)
#pragma unroll
      for (int it = 0; it < 2; ++it) {
        int idx = tid + it * 256;
        int r = idx >> 3, c8 = idx & 7;
        *(uint4*)(&kbuf[1 - cbuf][r * 72 + c8 * 8]) = kst[it];
      }
    }
    __syncthreads();  // drains V DMA (vmcnt) + K ds_writes before next chunk
  }

  // ---- epilogue: reduce l across lane-groups and waves, normalize, store ----
#pragma unroll
  for (int i = 0; i < 4; ++i) {
    float v = la[i];
    v += __shfl_xor(v, 16);
    v += __shfl_xor(v, 32);
    if (lane < 16) lred[w][i * 16 + lane] = v;
  }
  __syncthreads();
#pragma unroll
  for (int i = 0; i < 4; ++i) {
    float4_t lv = {0.f, 0.f, 0.f, 0.f};
#pragma unroll
    for (int ww = 0; ww < 4; ++ww)
      lv += *(const float4_t*)(&lred[ww][i * 16 + 4 * G]);
    float4_t inv;
#pragma unroll
    for (int r = 0; r < 4; ++r) inv[r] = 1.0f / lv[r];
#pragma unroll
    for (int ht = 0; ht < 5; ++ht)
#pragma unroll
      for (int r = 0; r < 4; ++r)
        out[(size_t)(b * Tn + tblk + i * 16 + 4 * G + r) * Hn + w * 80 + ht * 16 + l15] =
            oacc[i][ht][r] * inv[r];
  }
}

// ---------------------------------------------------------------------------
extern "C" void kernel_launch(void* const* d_in, const int* in_sizes, int n_in,
                              void* d_out, int out_size, void* d_ws, size_t ws_size,
                              hipStream_t stream) {
  const float* tokens  = (const float*)d_in[0];  // [4,4096,320]
  const float* context = (const float*)d_in[1];  // [4,4096,768]
  const float* Wq      = (const float*)d_in[2];  // [64,320]
  const float* Wk      = (const float*)d_in[3];  // [64,768]
  const float* Wv      = (const float*)d_in[4];  // [320,768]

  _Float16* Qws = (_Float16*)d_ws;                       // 16384*64 halves (2 MB)
  _Float16* Kws = Qws + (size_t)16384 * 64;              // 16384*64 halves (2 MB)
  _Float16* Vws = Kws + (size_t)16384 * 64;              // 16384*320 halves (10 MB, swizzled)

  proj_kernel<320, 64, 0><<<dim3(128, 1), 256, 0, stream>>>(tokens, Wq, Qws);
  proj_kernel<768, 64, 1><<<dim3(128, 1), 256, 0, stream>>>(context, Wk, Kws);
  proj_kernel<768, 80, 2><<<dim3(128, 4), 256, 0, stream>>>(context, Wv, Vws);
  flash_kernel<<<dim3(256), 256, 0, stream>>>(Qws, Kws, Vws, (float*)d_out);
}

// Round 2
// 229.583 us; speedup vs baseline: 1.4794x; 1.4794x over previous
//
#include <hip/hip_runtime.h>
#include <hip/hip_bf16.h>

typedef _Float16 half4_t  __attribute__((ext_vector_type(4)));
typedef _Float16 half8_t  __attribute__((ext_vector_type(8)));
typedef float    float4_t __attribute__((ext_vector_type(4)));

#define MFMA16x32(a, b, c) __builtin_amdgcn_mfma_f32_16x16x32_f16(a, b, c, 0, 0, 0)

static constexpr int Tn = 4096, Sn = 4096, Hn = 320;

__device__ __forceinline__ void async16(const _Float16* g, _Float16* l) {
  __builtin_amdgcn_global_load_lds(
      (const __attribute__((address_space(1))) void*)g,
      (__attribute__((address_space(3))) void*)l, 16, 0, 0);
}

// ---------------------------------------------------------------------------
// Projection OUT[16384 x NT] = A[16384 x KTOT] * W[NT-slice x KTOT]^T, fp32->fp16.
// M-tile 64 (grid.x=256), k-chunk 64, register-prefetched staging.
// NT==64 (Q/K): natural [m][64] output, scale applied (Q folds 1/8 * log2e).
// NT==160 (V, grid.y=2): epilogue LDS-bounce emits 16x16x32 B-fragment blocks:
//   block (c2b over s/32, ht over h/16): lane L holds V[s=8*(L>>4)+j][h=L&15].
// ---------------------------------------------------------------------------
template <int KTOT, int NT>
__global__ __launch_bounds__(256, 2)
void proj_kernel(const float* __restrict__ A, const float* __restrict__ W,
                 _Float16* __restrict__ out, float sc) {
  constexpr int NCH = KTOT / 64;
  constexpr int NTIL = NT / 16;
  __shared__ alignas(16) _Float16 Ach[64 * 72];   // stride 144 B: 2-way banks = free
  __shared__ alignas(16) _Float16 Bch[NT * 72];

  const int tid = threadIdx.x, w = tid >> 6, lane = tid & 63;
  const int G = lane >> 4, l15 = lane & 15;
  const int m0 = blockIdx.x * 64, n0 = blockIdx.y * NT;

  float4_t acc[NTIL];
#pragma unroll
  for (int nt = 0; nt < NTIL; ++nt) acc[nt] = {0.f, 0.f, 0.f, 0.f};

  float4_t areg[4], wreg[NTIL];
  auto ldA = [&](int kc) {
#pragma unroll
    for (int t = 0; t < 4; ++t) {
      int idx = t * 256 + tid;
      areg[t] = *(const float4_t*)(A + (size_t)(m0 + (idx >> 4)) * KTOT + kc * 64 + (idx & 15) * 4);
    }
  };
  auto ldW = [&](int kc) {
#pragma unroll
    for (int t = 0; t < NTIL; ++t) {
      int idx = t * 256 + tid;
      wreg[t] = *(const float4_t*)(W + (size_t)(n0 + (idx >> 4)) * KTOT + kc * 64 + (idx & 15) * 4);
    }
  };

  ldA(0); ldW(0);
  for (int kc = 0; kc < NCH; ++kc) {
    __syncthreads();  // previous chunk's frag reads done
#pragma unroll
    for (int t = 0; t < 4; ++t) {
      int idx = t * 256 + tid;
      half4_t h = {(_Float16)areg[t][0], (_Float16)areg[t][1], (_Float16)areg[t][2], (_Float16)areg[t][3]};
      *(half4_t*)(Ach + (idx >> 4) * 72 + (idx & 15) * 4) = h;
    }
#pragma unroll
    for (int t = 0; t < NTIL; ++t) {
      int idx = t * 256 + tid;
      half4_t h = {(_Float16)wreg[t][0], (_Float16)wreg[t][1], (_Float16)wreg[t][2], (_Float16)wreg[t][3]};
      *(half4_t*)(Bch + (idx >> 4) * 72 + (idx & 15) * 4) = h;
    }
    __syncthreads();
    if (kc + 1 < NCH) { ldA(kc + 1); ldW(kc + 1); }  // prefetch overlaps MFMA
#pragma unroll
    for (int c = 0; c < 2; ++c) {
      half8_t af = *(const half8_t*)(Ach + (w * 16 + l15) * 72 + c * 32 + 8 * G);
#pragma unroll
      for (int nt = 0; nt < NTIL; ++nt) {
        half8_t bf = *(const half8_t*)(Bch + (nt * 16 + l15) * 72 + c * 32 + 8 * G);
        acc[nt] = MFMA16x32(af, bf, acc[nt]);
      }
    }
  }

  if constexpr (NT == 64) {
#pragma unroll
    for (int nt = 0; nt < NTIL; ++nt)
#pragma unroll
      for (int r = 0; r < 4; ++r)
        out[(size_t)(m0 + w * 16 + 4 * G + r) * 64 + nt * 16 + l15] = (_Float16)(acc[nt][r] * sc);
  } else {
    // bounce C-regs (4 consecutive s per lane) -> [h][s] tile -> read 8-consecutive-s frags
    __syncthreads();
#pragma unroll
    for (int nt = 0; nt < NTIL; ++nt) {
      half4_t h = {(_Float16)acc[nt][0], (_Float16)acc[nt][1], (_Float16)acc[nt][2], (_Float16)acc[nt][3]};
      *(half4_t*)(Bch + (nt * 16 + l15) * 72 + w * 16 + 4 * G) = h;
    }
    __syncthreads();
#pragma unroll
    for (int rep = 0; rep < 5; ++rep) {
      int idx = w * 5 + rep;
      int c2 = idx / 10, htl = idx % 10;
      half8_t fr = *(const half8_t*)(Bch + (htl * 16 + l15) * 72 + c2 * 32 + 8 * G);
      int sg = m0 + c2 * 32;
      int b = sg >> 12, c2b = (sg & 4095) >> 5;
      int htg = blockIdx.y * 10 + htl;
      *(half8_t*)(out + ((size_t)((b * 128 + c2b) * 20 + htg)) * 512 + lane * 8) = fr;
    }
  }
}

// ---------------------------------------------------------------------------
// Flash cross-attention, s-split. Grid 512 = 4b x 64 t-blocks x 2 s-halves
// (XCD swizzle: b=(bx&7)>>1, sh=bx&1 so each XCD keeps one (b,sh) K/V slice).
// 55 KB LDS -> 2 blocks/CU: one block computes while the other drains its
// barrier. chunk=32 s; S^T = K*Q^T (waves split s-tile x t-half); P -> LDS
// [t][s] tile; PV uses K=32 MFMA, waves split by h (80 each, V never dup'd).
// No max-subtraction (|scores| small); partial O (fp16) + l (fp32) to ws.
// ---------------------------------------------------------------------------
__global__ __launch_bounds__(256, 2)
void flash_kernel(const _Float16* __restrict__ Qg, const _Float16* __restrict__ Kg,
                  const _Float16* __restrict__ Vt, _Float16* __restrict__ Op,
                  float* __restrict__ lp) {
  __shared__ alignas(16) _Float16 kbuf[32 * 72];      // single-buffered (reg-prefetch)
  __shared__ alignas(16) _Float16 pbuf[64 * 72];      // P as [t][s+pad]
  __shared__ alignas(16) _Float16 vbuf[2][10240];     // frag blocks, DMA double-buffer
  __shared__ float lred[4][32];

  const int tid = threadIdx.x, w = tid >> 6, lane = tid & 63;
  const int G = lane >> 4, l15 = lane & 15;
  const int bx = blockIdx.x;
  const int b = (bx & 7) >> 1, sh = bx & 1, tb = bx >> 3;
  const int tblk = tb * 64, sbase = sh * 2048;
  const int th = w >> 1, stile = w & 1;
  const int kr = tid >> 3, kc8 = (tid & 7) * 8;

  half8_t qf[2][2];  // B-frags for this wave's 32 t, resident all kernel
#pragma unroll
  for (int tt = 0; tt < 2; ++tt)
#pragma unroll
    for (int c = 0; c < 2; ++c)
      qf[tt][c] = *(const half8_t*)(Qg + (size_t)(b * Tn + tblk + th * 32 + tt * 16 + l15) * 64 + c * 32 + 8 * G);

  float4_t oacc[2][5][2];  // [tt][ht][ib] -> O[t=tt*16+..][h=w*80+ht*16+..]; split later
  // NOTE: use flat [4][5] layout below instead
  float4_t oa[4][5];
#pragma unroll
  for (int tt = 0; tt < 4; ++tt)
#pragma unroll
    for (int ht = 0; ht < 5; ++ht) oa[tt][ht] = {0.f, 0.f, 0.f, 0.f};
  float la[2] = {0.f, 0.f};

  const size_t vbase = (size_t)b * 1310720;  // halves: 4096*320

  // prologue: chunk 0
  {
    uint4 k0 = *(const uint4*)(Kg + (size_t)(b * Sn + sbase + kr) * 64 + kc8);
    *(uint4*)(&kbuf[kr * 72 + kc8]) = k0;
    const size_t voff = vbase + (size_t)(sh * 64) * 10240;
#pragma unroll
    for (int r = 0; r < 5; ++r) {
      int off = (w * 5 + r) * 512 + lane * 8;
      async16(Vt + voff + off, &vbuf[0][off]);
    }
  }
  __syncthreads();

  for (int n = 0; n < 64; ++n) {
    const int cb = n & 1;
    const bool more = (n < 63);
    uint4 kst;
    if (more)
      kst = *(const uint4*)(Kg + (size_t)(b * Sn + sbase + (n + 1) * 32 + kr) * 64 + kc8);

    // ---- S^T phase: wave (stile, th) -> S^T[16 s][32 t] ----
    float4_t sa[2] = {{0.f, 0.f, 0.f, 0.f}, {0.f, 0.f, 0.f, 0.f}};
#pragma unroll
    for (int c = 0; c < 2; ++c) {
      half8_t af = *(const half8_t*)(&kbuf[(stile * 16 + l15) * 72 + c * 32 + 8 * G]);
#pragma unroll
      for (int tt = 0; tt < 2; ++tt) sa[tt] = MFMA16x32(af, qf[tt][c], sa[tt]);
    }
#pragma unroll
    for (int tt = 0; tt < 2; ++tt) {
      float e0 = exp2f(sa[tt][0]), e1 = exp2f(sa[tt][1]);
      float e2 = exp2f(sa[tt][2]), e3 = exp2f(sa[tt][3]);
      la[tt] += (e0 + e1) + (e2 + e3);
      half4_t p = {(_Float16)e0, (_Float16)e1, (_Float16)e2, (_Float16)e3};
      *(half4_t*)(&pbuf[(th * 32 + tt * 16 + l15) * 72 + stile * 16 + 4 * G]) = p;
    }
    __syncthreads();  // B1: P visible; kbuf reads retired

    if (more) {  // overlap next chunk's V DMA + K write with PV compute
      const size_t voff = vbase + (size_t)(sh * 64 + n + 1) * 10240;
#pragma unroll
      for (int r = 0; r < 5; ++r) {
        int off = (w * 5 + r) * 512 + lane * 8;
        async16(Vt + voff + off, &vbuf[1 - cb][off]);
      }
      *(uint4*)(&kbuf[kr * 72 + kc8]) = kst;
    }

    // ---- PV phase: wave w -> h in [w*80, w*80+80), all 64 t, K=32 MFMA ----
    half8_t pa[4];
#pragma unroll
    for (int tt = 0; tt < 4; ++tt)
      pa[tt] = *(const half8_t*)(&pbuf[(tt * 16 + l15) * 72 + 8 * G]);
#pragma unroll
    for (int ht = 0; ht < 5; ++ht) {
      half8_t vb = *(const half8_t*)(&vbuf[cb][(w * 5 + ht) * 512 + lane * 8]);
#pragma unroll
      for (int tt = 0; tt < 4; ++tt) oa[tt][ht] = MFMA16x32(pa[tt], vb, oa[tt][ht]);
    }
    __syncthreads();  // B2: drains V DMA + K/P hazards
  }

  // ---- epilogue: l reduction + partial stores ----
#pragma unroll
  for (int tt = 0; tt < 2; ++tt) {
    float v = la[tt];
    v += __shfl_xor(v, 16);
    v += __shfl_xor(v, 32);
    if (lane < 16) lred[w][tt * 16 + lane] = v;
  }
  __syncthreads();
  if (stile == 0 && lane < 16) {
#pragma unroll
    for (int tt = 0; tt < 2; ++tt) {
      float lt = lred[w][tt * 16 + lane] + lred[w + 1][tt * 16 + lane];
      lp[(size_t)sh * 16384 + b * Tn + tblk + th * 32 + tt * 16 + lane] = lt;
    }
  }
  _Float16* myO = Op + (size_t)sh * 5242880;
#pragma unroll
  for (int tt = 0; tt < 4; ++tt)
#pragma unroll
    for (int ht = 0; ht < 5; ++ht)
#pragma unroll
      for (int r = 0; r < 4; ++r)
        myO[(size_t)(b * Tn + tblk + tt * 16 + 4 * G + r) * Hn + w * 80 + ht * 16 + l15] =
            (_Float16)oa[tt][ht][r];
}

// ---------------------------------------------------------------------------
__global__ __launch_bounds__(256)
void combine_kernel(const _Float16* __restrict__ O0, const _Float16* __restrict__ O1,
                    const float* __restrict__ l0, const float* __restrict__ l1,
                    float* __restrict__ out) {
  const int tid = threadIdx.x;
  const int base = blockIdx.x * 1280;  // 16 rows x 80 float4 per block
#pragma unroll
  for (int it = 0; it < 5; ++it) {
    int lin = base + it * 256 + tid;
    int row = lin / 80;
    float inv = 1.0f / (l0[row] + l1[row]);
    half4_t a = *(const half4_t*)(O0 + (size_t)lin * 4);
    half4_t c = *(const half4_t*)(O1 + (size_t)lin * 4);
    float4_t o = {((float)a[0] + (float)c[0]) * inv, ((float)a[1] + (float)c[1]) * inv,
                  ((float)a[2] + (float)c[2]) * inv, ((float)a[3] + (float)c[3]) * inv};
    *(float4_t*)(out + (size_t)lin * 4) = o;
  }
}

// ---------------------------------------------------------------------------
extern "C" void kernel_launch(void* const* d_in, const int* in_sizes, int n_in,
                              void* d_out, int out_size, void* d_ws, size_t ws_size,
                              hipStream_t stream) {
  const float* tokens  = (const float*)d_in[0];  // [4,4096,320]
  const float* context = (const float*)d_in[1];  // [4,4096,768]
  const float* Wq      = (const float*)d_in[2];  // [64,320]
  const float* Wk      = (const float*)d_in[3];  // [64,768]
  const float* Wv      = (const float*)d_in[4];  // [320,768]

  _Float16* Qws = (_Float16*)d_ws;                 // 1,048,576 halves (2 MB)
  _Float16* Kws = Qws + (size_t)1048576;           // 2 MB
  _Float16* Vws = Kws + (size_t)1048576;           // 5,242,880 halves (10 MB, frag blocks)
  _Float16* O0  = Vws + (size_t)5242880;           // fp16 partials, 10 MB each
  _Float16* O1  = O0 + (size_t)5242880;
  float*    l0  = (float*)(O1 + (size_t)5242880);  // 64 KB each
  float*    l1  = l0 + 16384;

  const float qsc = 0.125f * 1.44269504088896f;  // 1/sqrt(64) * log2(e)
  proj_kernel<320, 64><<<dim3(256, 1), 256, 0, stream>>>(tokens, Wq, Qws, qsc);
  proj_kernel<768, 64><<<dim3(256, 1), 256, 0, stream>>>(context, Wk, Kws, 1.0f);
  proj_kernel<768, 160><<<dim3(256, 2), 256, 0, stream>>>(context, Wv, Vws, 1.0f);
  flash_kernel<<<dim3(512), 256, 0, stream>>>(Qws, Kws, Vws, O0, l0);
  combine_kernel<<<dim3(1024), 256, 0, stream>>>(O0, O1, l0, l1, (float*)d_out);
}

// Round 4
// 205.006 us; speedup vs baseline: 1.6568x; 1.1199x over previous
//
#include <hip/hip_runtime.h>
#include <hip/hip_bf16.h>

typedef _Float16 half4_t  __attribute__((ext_vector_type(4)));
typedef _Float16 half8_t  __attribute__((ext_vector_type(8)));
typedef float    float4_t __attribute__((ext_vector_type(4)));

#define MFMA16x32(a, b, c) __builtin_amdgcn_mfma_f32_16x16x32_f16(a, b, c, 0, 0, 0)

// ---------------------------------------------------------------------------
// Fused QKV projection. grid.x = 1024: [0,512) V, [512,768) K, [768,1024) Q.
// OUT[m x NT] = A[m x KTOT] * W[NT x KTOT]^T, fp32 in -> fp16 out, M-tile 64.
// MODE 0: Q natural [m][64], scale 0.125*log2e folded in. MODE 1: K natural.
// MODE 2: V emitted as 16x16x32 B-fragment blocks: block (b, s-chunk32, htile):
//   lane L, j: V[h = ht*16 + (L&15)][s = ch*32 + 8*(L>>4) + j].
// ---------------------------------------------------------------------------
template <int KTOT, int NT, int MODE>
__device__ __forceinline__ void proj_body(const float* __restrict__ A,
                                          const float* __restrict__ W,
                                          _Float16* __restrict__ out, float sc,
                                          int m0, int n0, int htg0,
                                          _Float16* Ach, _Float16* Bch) {
  constexpr int NCH = KTOT / 64;
  constexpr int NTIL = NT / 16;
  const int tid = threadIdx.x, w = tid >> 6, lane = tid & 63;
  const int G = lane >> 4, l15 = lane & 15;

  float4_t acc[NTIL];
#pragma unroll
  for (int nt = 0; nt < NTIL; ++nt) acc[nt] = {0.f, 0.f, 0.f, 0.f};

  float4_t areg[4], wreg[NTIL];
  auto ldA = [&](int kc) {
#pragma unroll
    for (int t = 0; t < 4; ++t) {
      int idx = t * 256 + tid;
      areg[t] = *(const float4_t*)(A + (size_t)(m0 + (idx >> 4)) * KTOT + kc * 64 + (idx & 15) * 4);
    }
  };
  auto ldW = [&](int kc) {
#pragma unroll
    for (int t = 0; t < NTIL; ++t) {
      int idx = t * 256 + tid;
      wreg[t] = *(const float4_t*)(W + (size_t)(n0 + (idx >> 4)) * KTOT + kc * 64 + (idx & 15) * 4);
    }
  };

  ldA(0); ldW(0);
  for (int kc = 0; kc < NCH; ++kc) {
    __syncthreads();
#pragma unroll
    for (int t = 0; t < 4; ++t) {
      int idx = t * 256 + tid;
      half4_t h = {(_Float16)areg[t][0], (_Float16)areg[t][1], (_Float16)areg[t][2], (_Float16)areg[t][3]};
      *(half4_t*)(Ach + (idx >> 4) * 72 + (idx & 15) * 4) = h;
    }
#pragma unroll
    for (int t = 0; t < NTIL; ++t) {
      int idx = t * 256 + tid;
      half4_t h = {(_Float16)wreg[t][0], (_Float16)wreg[t][1], (_Float16)wreg[t][2], (_Float16)wreg[t][3]};
      *(half4_t*)(Bch + (idx >> 4) * 72 + (idx & 15) * 4) = h;
    }
    __syncthreads();
    if (kc + 1 < NCH) { ldA(kc + 1); ldW(kc + 1); }
#pragma unroll
    for (int c = 0; c < 2; ++c) {
      half8_t af = *(const half8_t*)(Ach + (w * 16 + l15) * 72 + c * 32 + 8 * G);
#pragma unroll
      for (int nt = 0; nt < NTIL; ++nt) {
        half8_t bf = *(const half8_t*)(Bch + (nt * 16 + l15) * 72 + c * 32 + 8 * G);
        acc[nt] = MFMA16x32(af, bf, acc[nt]);
      }
    }
  }

  if constexpr (MODE <= 1) {
#pragma unroll
    for (int nt = 0; nt < NTIL; ++nt)
#pragma unroll
      for (int r = 0; r < 4; ++r)
        out[(size_t)(m0 + w * 16 + 4 * G + r) * 64 + nt * 16 + l15] = (_Float16)(acc[nt][r] * sc);
  } else {
    // bounce C-regs through LDS: [h-local][s-local 64] tile, then frag-order stores
    __syncthreads();
#pragma unroll
    for (int nt = 0; nt < NTIL; ++nt) {
      half4_t h = {(_Float16)acc[nt][0], (_Float16)acc[nt][1], (_Float16)acc[nt][2], (_Float16)acc[nt][3]};
      *(half4_t*)(Bch + (nt * 16 + l15) * 72 + w * 16 + 4 * G) = h;
    }
    __syncthreads();
#pragma unroll
    for (int rep = 0; rep < 5; ++rep) {
      int idx = w * 5 + rep;
      int c2 = idx / 10, htl = idx % 10;
      half8_t fr = *(const half8_t*)(Bch + (htl * 16 + l15) * 72 + c2 * 32 + 8 * G);
      int sg = m0 + c2 * 32;
      int b = sg >> 12, c2b = (sg & 4095) >> 5;
      int htg = htg0 + htl;
      *(half8_t*)(out + ((size_t)((b * 128 + c2b) * 20 + htg)) * 512 + lane * 8) = fr;
    }
  }
}

__global__ __launch_bounds__(256, 2)
void qkv_proj_kernel(const float* __restrict__ tokens, const float* __restrict__ context,
                     const float* __restrict__ Wq, const float* __restrict__ Wk,
                     const float* __restrict__ Wv, _Float16* __restrict__ Q,
                     _Float16* __restrict__ K, _Float16* __restrict__ V) {
  __shared__ alignas(16) _Float16 smem[16128];  // Ach 64*72 + Bch 160*72
  _Float16* Ach = smem;
  _Float16* Bch = smem + 64 * 72;
  const int bx = blockIdx.x;
  const float qsc = 0.125f * 1.44269504088896f;  // 1/sqrt(64) * log2(e)
  if (bx < 512) {
    int y = bx >> 8, mb = bx & 255;
    proj_body<768, 160, 2>(context, Wv, V, 1.0f, mb * 64, y * 160, y * 10, Ach, Bch);
  } else if (bx < 768) {
    proj_body<768, 64, 1>(context, Wk, K, 1.0f, (bx - 512) * 64, 0, 0, Ach, Bch);
  } else {
    proj_body<320, 64, 0>(tokens, Wq, Q, qsc, (bx - 768) * 64, 0, 0, Ach, Bch);
  }
}

// ---------------------------------------------------------------------------
// Flash cross-attention, producer/consumer wave specialization.
// Grid 256 = 4b x 64 t-blocks (t=64), 512 threads, 1 block/CU.
// Waves 0-3 (PV): h-slice 80 each, V direct global->reg (frag layout), K=32 MFMA.
// Waves 4-7 (S^T): compute S^T(i+1)=K*Q^T while PV consumes P(i); stage K.
// kbuf/pbuf double-buffered in fragment-linear layout (all LDS wave-linear,
// conflict-free). ONE barrier per 32-s chunk. No softmax max-subtraction
// (scores tiny); l-normalize in epilogue. fp32 out directly.
// ---------------------------------------------------------------------------
__global__ __launch_bounds__(512, 2)
void flash_kernel(const _Float16* __restrict__ Qg, const _Float16* __restrict__ Kg,
                  const _Float16* __restrict__ Vt, float* __restrict__ out) {
  __shared__ alignas(16) _Float16 kbuf[2][2048];  // frag blocks (stile*2+c)*512 + lane*8
  __shared__ alignas(16) _Float16 pbuf[2][2048];  // frag blocks tt*512 + lane*8
  __shared__ float larr[2][4][16];
  __shared__ float linv[64];

  const int tid = threadIdx.x, w = tid >> 6, lane = tid & 63;
  const int G = lane >> 4, l15 = lane & 15;
  const int bx = blockIdx.x;
  const int b = (bx & 7) >> 1;                       // batch pinned per XCD pair
  const int tblk = ((bx & 1) * 32 + (bx >> 3)) * 64; // 64-query block

  const bool is_pv = (w < 4);
  const int sw = w - 4;                  // S^T wave index
  const int stile = sw & 1, tthalf = sw >> 1;
  const int t2 = tid & 255;              // K-staging slot (S^T waves)
  const int s_loc = t2 >> 3, e8 = t2 & 7;
  const int kdst = ((s_loc >> 4) * 2 + (e8 >> 2)) * 512 + ((e8 & 3) * 16 + (s_loc & 15)) * 8;
  const _Float16* kg = Kg + (size_t)(b * 4096) * 64 + s_loc * 64 + e8 * 8;
  const _Float16* vt_b = Vt + (size_t)b * 1310720;

  half8_t qf[2][2];
  float la[2] = {0.f, 0.f};
  float4_t oa[4][5];
#pragma unroll
  for (int tt = 0; tt < 4; ++tt)
#pragma unroll
    for (int ht = 0; ht < 5; ++ht) oa[tt][ht] = {0.f, 0.f, 0.f, 0.f};
  half8_t vcur[5], vnxt[5];

  // ---- prologue: stage K(0), K(1); load Q frags ----
  if (!is_pv) {
    uint4 k0 = *(const uint4*)(kg);
    uint4 k1 = *(const uint4*)(kg + 2048);
    *(uint4*)(&kbuf[0][kdst]) = k0;
    *(uint4*)(&kbuf[1][kdst]) = k1;
#pragma unroll
    for (int tt2 = 0; tt2 < 2; ++tt2) {
      int tt = tthalf * 2 + tt2;
#pragma unroll
      for (int c = 0; c < 2; ++c)
        qf[tt2][c] = *(const half8_t*)(Qg + (size_t)(b * 4096 + tblk + tt * 16 + l15) * 64 + c * 32 + 8 * G);
    }
  }
  __syncthreads();

  // ---- pre-step: S^T produces P(0); PV loads V(0) ----
  if (is_pv) {
#pragma unroll
    for (int ht = 0; ht < 5; ++ht)
      vcur[ht] = *(const half8_t*)(vt_b + (w * 5 + ht) * 512 + lane * 8);
  } else {
    half8_t af[2];
#pragma unroll
    for (int c = 0; c < 2; ++c)
      af[c] = *(const half8_t*)(&kbuf[0][(stile * 2 + c) * 512 + lane * 8]);
#pragma unroll
    for (int tt2 = 0; tt2 < 2; ++tt2) {
      float4_t sa = {0.f, 0.f, 0.f, 0.f};
#pragma unroll
      for (int c = 0; c < 2; ++c) sa = MFMA16x32(af[c], qf[tt2][c], sa);
      float e0 = exp2f(sa[0]), e1 = exp2f(sa[1]), e2 = exp2f(sa[2]), e3 = exp2f(sa[3]);
      la[tt2] += (e0 + e1) + (e2 + e3);
      int tt = tthalf * 2 + tt2;
      int Gp = stile * 2 + (G >> 1);
      half4_t p = {(_Float16)e0, (_Float16)e1, (_Float16)e2, (_Float16)e3};
      *(half4_t*)(&pbuf[0][tt * 512 + (Gp * 16 + l15) * 8 + 4 * (G & 1)]) = p;
    }
  }
  __syncthreads();

  // ---- main loop: step i consumes P(i)/V(i), produces P(i+1), stages K(i+2) ----
  for (int i = 0; i < 128; ++i) {
    if (is_pv) {
      if (i < 127) {
#pragma unroll
        for (int ht = 0; ht < 5; ++ht)
          vnxt[ht] = *(const half8_t*)(vt_b + (size_t)(i + 1) * 10240 + (w * 5 + ht) * 512 + lane * 8);
      }
      half8_t pa[4];
#pragma unroll
      for (int tt = 0; tt < 4; ++tt)
        pa[tt] = *(const half8_t*)(&pbuf[i & 1][tt * 512 + lane * 8]);
#pragma unroll
      for (int ht = 0; ht < 5; ++ht)
#pragma unroll
        for (int tt = 0; tt < 4; ++tt) oa[tt][ht] = MFMA16x32(pa[tt], vcur[ht], oa[tt][ht]);
#pragma unroll
      for (int ht = 0; ht < 5; ++ht) vcur[ht] = vnxt[ht];
    } else if (i < 127) {
      uint4 kreg;
      if (i < 126) kreg = *(const uint4*)(kg + (size_t)(i + 2) * 2048);
      half8_t af[2];
#pragma unroll
      for (int c = 0; c < 2; ++c)
        af[c] = *(const half8_t*)(&kbuf[(i + 1) & 1][(stile * 2 + c) * 512 + lane * 8]);
#pragma unroll
      for (int tt2 = 0; tt2 < 2; ++tt2) {
        float4_t sa = {0.f, 0.f, 0.f, 0.f};
#pragma unroll
        for (int c = 0; c < 2; ++c) sa = MFMA16x32(af[c], qf[tt2][c], sa);
        float e0 = exp2f(sa[0]), e1 = exp2f(sa[1]), e2 = exp2f(sa[2]), e3 = exp2f(sa[3]);
        la[tt2] += (e0 + e1) + (e2 + e3);
        int tt = tthalf * 2 + tt2;
        int Gp = stile * 2 + (G >> 1);
        half4_t p = {(_Float16)e0, (_Float16)e1, (_Float16)e2, (_Float16)e3};
        *(half4_t*)(&pbuf[(i + 1) & 1][tt * 512 + (Gp * 16 + l15) * 8 + 4 * (G & 1)]) = p;
      }
      if (i < 126) *(uint4*)(&kbuf[i & 1][kdst]) = kreg;
    }
    __syncthreads();
  }

  // ---- epilogue: l reduction (S^T waves), normalize + store (PV waves) ----
  if (!is_pv) {
#pragma unroll
    for (int tt2 = 0; tt2 < 2; ++tt2) {
      float v = la[tt2];
      v += __shfl_xor(v, 16);
      v += __shfl_xor(v, 32);
      if (lane < 16) larr[stile][tthalf * 2 + tt2][l15] = v;
    }
  }
  __syncthreads();
  if (tid < 64) linv[tid] = 1.0f / (larr[0][tid >> 4][tid & 15] + larr[1][tid >> 4][tid & 15]);
  __syncthreads();
  if (is_pv) {
#pragma unroll
    for (int tt = 0; tt < 4; ++tt)
#pragma unroll
      for (int r = 0; r < 4; ++r) {
        float inv = linv[tt * 16 + 4 * G + r];
        size_t row = (size_t)(b * 4096 + tblk + tt * 16 + 4 * G + r) * 320;
#pragma unroll
        for (int ht = 0; ht < 5; ++ht)
          out[row + w * 80 + ht * 16 + l15] = oa[tt][ht][r] * inv;
      }
  }
}

// ---------------------------------------------------------------------------
extern "C" void kernel_launch(void* const* d_in, const int* in_sizes, int n_in,
                              void* d_out, int out_size, void* d_ws, size_t ws_size,
                              hipStream_t stream) {
  const float* tokens  = (const float*)d_in[0];  // [4,4096,320]
  const float* context = (const float*)d_in[1];  // [4,4096,768]
  const float* Wq      = (const float*)d_in[2];  // [64,320]
  const float* Wk      = (const float*)d_in[3];  // [64,768]
  const float* Wv      = (const float*)d_in[4];  // [320,768]

  _Float16* Qws = (_Float16*)d_ws;           // 1,048,576 halves (2 MB)
  _Float16* Kws = Qws + (size_t)1048576;     // 2 MB
  _Float16* Vws = Kws + (size_t)1048576;     // 10 MB, fragment-block layout

  qkv_proj_kernel<<<dim3(1024), 256, 0, stream>>>(tokens, context, Wq, Wk, Wv,
                                                  Qws, Kws, Vws);
  flash_kernel<<<dim3(256), 512, 0, stream>>>(Qws, Kws, Vws, (float*)d_out);
}